// Round 1
// baseline (5254.078 us; speedup 1.0000x reference)
//
#include <hip/hip_runtime.h>
#include <math.h>

// Problem constants (fixed by the reference setup).
#define B 64
#define H 1024
#define V 16384
#define T 64
constexpr int KT = 32;                       // K-chunk staged in LDS
constexpr size_t TBV = (size_t)T * B * V;    // elements per [T,B,V] output

// ---------------- init: h=enc_h, c=enc_c, x=broadcast(init_input), mask=1 ----------------
__global__ __launch_bounds__(256) void k_init(
    const float* __restrict__ enc_h, const float* __restrict__ enc_c,
    const float* __restrict__ init_input,
    float* __restrict__ h, float* __restrict__ c,
    float* __restrict__ x, float* __restrict__ mask)
{
    int i = blockIdx.x * 256 + threadIdx.x;      // grid covers B*H = 65536
    if (i < B * H) {
        h[i] = enc_h[i];
        c[i] = enc_c[i];
        x[i] = init_input[i & (H - 1)];          // [1,H] broadcast over batch
    }
    if (i < B) mask[i] = 1.0f;
}

// ---------------- gates GEMM partials ----------------
// gates[b,m] = sum_k x[b,k]*W_ih[m,k] + sum_k h[b,k]*W_hh[m,k]
// grid = 64 n-tiles * 8 k-splits = 512 blocks; each block: 64 rows x 64 cols, K=256.
// gpart[ks][b][m] holds the partial for k-split ks.
__global__ __launch_bounds__(256) void k_gates(
    const float* __restrict__ x, const float* __restrict__ h,
    const float* __restrict__ W_ih, const float* __restrict__ W_hh,
    float* __restrict__ gpart)
{
    const int nt   = blockIdx.x >> 3;    // 0..63
    const int ks   = blockIdx.x & 7;     // 0..7
    const int pair = ks >> 2;            // 0: x/W_ih, 1: h/W_hh
    const int kbase = (ks & 3) * 256;
    const float* __restrict__ A = pair ? h : x;
    const float* __restrict__ W = pair ? W_hh : W_ih;

    __shared__ __align__(16) float a_lds[KT][68];
    __shared__ __align__(16) float w_lds[KT][68];

    const int tid = threadIdx.x;
    const int tb = tid >> 4;   // 0..15 -> b_base = tb*4
    const int tn = tid & 15;   // 0..15 -> n_base = tn*4
    float acc[4][4];
#pragma unroll
    for (int i = 0; i < 4; ++i)
#pragma unroll
        for (int j = 0; j < 4; ++j) acc[i][j] = 0.f;

    const int kk = tid & 31;
    const int r  = tid >> 5;   // 0..7

    for (int kc = 0; kc < 256 / KT; ++kc) {
        const int k0 = kbase + kc * KT;
#pragma unroll
        for (int j = 0; j < 8; ++j) {
            int row = r * 8 + j;
            a_lds[kk][row] = A[row * H + k0 + kk];
            w_lds[kk][row] = W[(nt * 64 + row) * H + k0 + kk];
        }
        __syncthreads();
#pragma unroll
        for (int k2 = 0; k2 < KT; ++k2) {
            float4 av = *(const float4*)&a_lds[k2][tb * 4];
            float4 wv = *(const float4*)&w_lds[k2][tn * 4];
            acc[0][0] = fmaf(av.x, wv.x, acc[0][0]);
            acc[0][1] = fmaf(av.x, wv.y, acc[0][1]);
            acc[0][2] = fmaf(av.x, wv.z, acc[0][2]);
            acc[0][3] = fmaf(av.x, wv.w, acc[0][3]);
            acc[1][0] = fmaf(av.y, wv.x, acc[1][0]);
            acc[1][1] = fmaf(av.y, wv.y, acc[1][1]);
            acc[1][2] = fmaf(av.y, wv.z, acc[1][2]);
            acc[1][3] = fmaf(av.y, wv.w, acc[1][3]);
            acc[2][0] = fmaf(av.z, wv.x, acc[2][0]);
            acc[2][1] = fmaf(av.z, wv.y, acc[2][1]);
            acc[2][2] = fmaf(av.z, wv.z, acc[2][2]);
            acc[2][3] = fmaf(av.z, wv.w, acc[2][3]);
            acc[3][0] = fmaf(av.w, wv.x, acc[3][0]);
            acc[3][1] = fmaf(av.w, wv.y, acc[3][1]);
            acc[3][2] = fmaf(av.w, wv.z, acc[3][2]);
            acc[3][3] = fmaf(av.w, wv.w, acc[3][3]);
        }
        __syncthreads();
    }

    float* outp = gpart + (size_t)ks * B * 4096;
#pragma unroll
    for (int i = 0; i < 4; ++i) {
        float4 v = make_float4(acc[i][0], acc[i][1], acc[i][2], acc[i][3]);
        *(float4*)&outp[(size_t)(tb * 4 + i) * 4096 + nt * 64 + tn * 4] = v;
    }
}

// ---------------- reduce gate partials + LSTM pointwise ----------------
__global__ __launch_bounds__(256) void k_lstm(
    const float* __restrict__ gpart,
    const float* __restrict__ b_ih, const float* __restrict__ b_hh,
    float* __restrict__ h, float* __restrict__ c)
{
    int idx = blockIdx.x * 256 + threadIdx.x;   // 0..B*H-1
    int b = idx >> 10, j = idx & 1023;
    float s[4];
#pragma unroll
    for (int g = 0; g < 4; ++g) {
        int m = g * H + j;
        float v = b_ih[m] + b_hh[m];
#pragma unroll
        for (int ksp = 0; ksp < 8; ++ksp)
            v += gpart[(size_t)ksp * B * 4096 + (size_t)b * 4096 + m];
        s[g] = v;
    }
    float ig = 1.f / (1.f + expf(-s[0]));
    float fg = 1.f / (1.f + expf(-s[1]));
    float gg = tanhf(s[2]);
    float og = 1.f / (1.f + expf(-s[3]));
    float cn = fg * c[idx] + ig * gg;
    float hn = og * tanhf(cn);
    c[idx] = cn;
    h[idx] = hn;
}

// ---------------- logits GEMM partials ----------------
// logit[b,v] = sum_k h[b,k]*W_out[v,k]   (bias added in k_argmax)
// grid = 256 n-tiles * 2 k-splits = 512 blocks. ks=0 -> d_out logits region, ks=1 -> lpart.
__global__ __launch_bounds__(256) void k_logits(
    const float* __restrict__ h, const float* __restrict__ W_out,
    float* __restrict__ out0, float* __restrict__ lpart)
{
    const int nt = blockIdx.x >> 1;   // 0..255
    const int ks = blockIdx.x & 1;
    const int kbase = ks * 512;
    float* __restrict__ dst = ks ? lpart : out0;

    __shared__ __align__(16) float a_lds[KT][68];
    __shared__ __align__(16) float w_lds[KT][68];

    const int tid = threadIdx.x;
    const int tb = tid >> 4;
    const int tn = tid & 15;
    float acc[4][4];
#pragma unroll
    for (int i = 0; i < 4; ++i)
#pragma unroll
        for (int j = 0; j < 4; ++j) acc[i][j] = 0.f;

    const int kk = tid & 31;
    const int r  = tid >> 5;

    for (int kc = 0; kc < 512 / KT; ++kc) {
        const int k0 = kbase + kc * KT;
#pragma unroll
        for (int j = 0; j < 8; ++j) {
            int row = r * 8 + j;
            a_lds[kk][row] = h[row * H + k0 + kk];
            w_lds[kk][row] = W_out[(size_t)(nt * 64 + row) * H + k0 + kk];
        }
        __syncthreads();
#pragma unroll
        for (int k2 = 0; k2 < KT; ++k2) {
            float4 av = *(const float4*)&a_lds[k2][tb * 4];
            float4 wv = *(const float4*)&w_lds[k2][tn * 4];
            acc[0][0] = fmaf(av.x, wv.x, acc[0][0]);
            acc[0][1] = fmaf(av.x, wv.y, acc[0][1]);
            acc[0][2] = fmaf(av.x, wv.z, acc[0][2]);
            acc[0][3] = fmaf(av.x, wv.w, acc[0][3]);
            acc[1][0] = fmaf(av.y, wv.x, acc[1][0]);
            acc[1][1] = fmaf(av.y, wv.y, acc[1][1]);
            acc[1][2] = fmaf(av.y, wv.z, acc[1][2]);
            acc[1][3] = fmaf(av.y, wv.w, acc[1][3]);
            acc[2][0] = fmaf(av.z, wv.x, acc[2][0]);
            acc[2][1] = fmaf(av.z, wv.y, acc[2][1]);
            acc[2][2] = fmaf(av.z, wv.z, acc[2][2]);
            acc[2][3] = fmaf(av.z, wv.w, acc[2][3]);
            acc[3][0] = fmaf(av.w, wv.x, acc[3][0]);
            acc[3][1] = fmaf(av.w, wv.y, acc[3][1]);
            acc[3][2] = fmaf(av.w, wv.z, acc[3][2]);
            acc[3][3] = fmaf(av.w, wv.w, acc[3][3]);
        }
        __syncthreads();
    }

#pragma unroll
    for (int i = 0; i < 4; ++i) {
        float4 v = make_float4(acc[i][0], acc[i][1], acc[i][2], acc[i][3]);
        *(float4*)&dst[(size_t)(tb * 4 + i) * V + nt * 64 + tn * 4] = v;
    }
}

// ---------------- finalize logits (+bias), argmax, one-hot, mask, x=emb[idx] ----------------
__global__ __launch_bounds__(256) void k_argmax(
    float* __restrict__ logit_t,            // d_out logits for step t (holds ks=0 partial)
    const float* __restrict__ lpart,        // ks=1 partial
    const float* __restrict__ b_out,
    const float* __restrict__ embedding,
    const int* __restrict__ eos_ptr,
    float* __restrict__ mask,               // [B]
    float* __restrict__ x,                  // [B,H]
    float* __restrict__ predicts_t,         // d_out predicts for step t [B,V] (pre-zeroed)
    float* __restrict__ masks_t)            // d_out masks for step t [B]
{
    const int b = blockIdx.x, tid = threadIdx.x;
    __shared__ float sval[256];
    __shared__ int   sidx[256];

    float best = -INFINITY;
    int bi = 0;
    for (int v = tid; v < V; v += 256) {
        size_t off = (size_t)b * V + v;
        float val = logit_t[off] + lpart[off] + b_out[v];
        logit_t[off] = val;
        if (val > best) { best = val; bi = v; }   // ascending scan -> earliest max kept
    }
    sval[tid] = best; sidx[tid] = bi;
    __syncthreads();
    for (int s = 128; s > 0; s >>= 1) {
        if (tid < s) {
            float v2 = sval[tid + s]; int i2 = sidx[tid + s];
            if (v2 > sval[tid] || (v2 == sval[tid] && i2 < sidx[tid])) {
                sval[tid] = v2; sidx[tid] = i2;
            }
        }
        __syncthreads();
    }
    int idx = sidx[0];
    if (tid == 0) {
        predicts_t[(size_t)b * V + idx] = 1.0f;
        float mb = mask[b];
        masks_t[b] = mb;                          // output OLD mask (pre-update)
        if (idx == *eos_ptr) mask[b] = 0.0f;      // mask *= (1 - onehot[eos])
    }
    // x[b,:] = embedding[idx,:]
    const float4* emb4 = (const float4*)(embedding + (size_t)idx * H);
    float4* x4 = (float4*)(x + (size_t)b * H);
    for (int k = tid; k < H / 4; k += 256) x4[k] = emb4[k];
}

extern "C" void kernel_launch(void* const* d_in, const int* in_sizes, int n_in,
                              void* d_out, int out_size, void* d_ws, size_t ws_size,
                              hipStream_t stream)
{
    (void)in_sizes; (void)n_in; (void)out_size; (void)ws_size;

    const float* enc_h = (const float*)d_in[0];
    const float* enc_c = (const float*)d_in[1];
    const float* W_ih  = (const float*)d_in[2];
    const float* W_hh  = (const float*)d_in[3];
    const float* b_ih  = (const float*)d_in[4];
    const float* b_hh  = (const float*)d_in[5];
    const float* W_out = (const float*)d_in[6];
    const float* b_out = (const float*)d_in[7];
    const float* emb   = (const float*)d_in[8];
    const float* init_input = (const float*)d_in[9];
    const int* eos_ptr = (const int*)d_in[11];   // d_in[10] = max_len (compile-time T=64)

    float* out = (float*)d_out;
    float* ws  = (float*)d_ws;
    // workspace carve (floats): total ~12.8 MB
    float* h     = ws;                 // B*H
    float* c     = h + B * H;          // B*H
    float* x     = c + B * H;          // B*H
    float* mask  = x + B * H;          // B
    float* gpart = mask + 64;          // 8*B*4096
    float* lpart = gpart + 8 * B * 4096; // B*V

    // predicts region is mostly zeros: clear once per launch, scatter ones per step
    hipMemsetAsync(d_out, 0, TBV * sizeof(float), stream);
    k_init<<<256, 256, 0, stream>>>(enc_h, enc_c, init_input, h, c, x, mask);

    for (int t = 0; t < T; ++t) {
        float* predicts_t = out + (size_t)t * B * V;
        float* logits_t   = out + TBV + (size_t)t * B * V;
        float* masks_t    = out + 2 * TBV + (size_t)t * B;

        k_gates<<<512, 256, 0, stream>>>(x, h, W_ih, W_hh, gpart);
        k_lstm<<<256, 256, 0, stream>>>(gpart, b_ih, b_hh, h, c);
        k_logits<<<512, 256, 0, stream>>>(h, W_out, logits_t, lpart);
        k_argmax<<<64, 256, 0, stream>>>(logits_t, lpart, b_out, emb, eos_ptr,
                                         mask, x, predicts_t, masks_t);
    }
}